// Round 2
// baseline (153.565 us; speedup 1.0000x reference)
//
#include <hip/hip_runtime.h>
#include <hip/hip_cooperative_groups.h>

namespace cg = cooperative_groups;

// Problem constants: B=4, L=256, DM=256, DL=64, R=256, K=1,
// N_ITER=4, STEPSIZE=1.0, DAMPING=0.0, REG=1.0.
//
// Algebraic collapse (verified exact, absmax 0.0 in R1): output is ONE pass:
//   qz   = valid * softmax(x, -1)                       (B*L, DM)
//   t[z] = sum_i qz[z,i,:]                              (B, DM)
//   wbar[l,d] = mean_c W[l,c,d]                         (2, R)
//   P[b,a]   = sum_{l,d} V[l,b,d]*wbar[l,d]*U[l,a,d]    (DM, DM)
//   out[z,i,a] = x[z,i,a] + valid_i * sum_b (t[z,b]-qz[z,i,b]) * P[b,a]
//
// R4: single cooperative kernel, 256 blocks x 256 threads, grid.sync between
// phases. Rationale from R1 counters: timed path is dominated by harness
// 268MB workspace poison fills (41.5us each, 80% HBM peak); our controllable
// share is ~31us = 2 launches + redundant per-block t-colsum + 16-block
// P-GEMM tail. This version: 1 launch, t computed once, P-GEMM on 64 blocks,
// syncless wave-per-row softmax.

#define DMv 256
#define LLv 256
#define RRv 256
#define DLv 64

__global__ __launch_bounds__(256) void k_all(
    const float* __restrict__ x, const int* __restrict__ mask,
    const float* __restrict__ U, const float* __restrict__ V,
    const float* __restrict__ W, float* __restrict__ qz,
    float* __restrict__ P, float* __restrict__ tws,
    float* __restrict__ wbws, float* __restrict__ out) {
    // pad-36 rows: 144B row stride -> 16B-aligned float4/float2 LDS ops legal.
    __shared__ float As[64][36];
    __shared__ float Bs[64][36];
    __shared__ float aux[512];
    const int tid = threadIdx.x;
    const int blk = blockIdx.x;
    const int lane = tid & 63;
    const int wv = tid >> 6;

    // ---------- phase 1: softmax (wave-per-row, no syncs) + wbar ----------
    {
        const int row = (blk << 2) + wv;          // 0..1023
        float4 v = *(const float4*)(x + row * DMv + (lane << 2));
        float m = fmaxf(fmaxf(v.x, v.y), fmaxf(v.z, v.w));
#pragma unroll
        for (int o = 32; o > 0; o >>= 1) m = fmaxf(m, __shfl_xor(m, o, 64));
        float e0 = __expf(v.x - m), e1 = __expf(v.y - m);
        float e2 = __expf(v.z - m), e3 = __expf(v.w - m);
        float s = e0 + e1 + e2 + e3;
#pragma unroll
        for (int o = 32; o > 0; o >>= 1) s += __shfl_xor(s, o, 64);
        float4 q;
        if (mask[row] != 0) {
            q.x = e0 / s; q.y = e1 / s; q.z = e2 / s; q.w = e3 / s;
        } else {
            q.x = 0.f; q.y = 0.f; q.z = 0.f; q.w = 0.f;
        }
        *(float4*)(qz + row * DMv + (lane << 2)) = q;
    }
    if (blk >= 248) {
        // wbar[l][d0..d0+63], one 64-col chunk per block (8 chunks total)
        const int j = blk - 248, l = j >> 2, d0 = (j & 3) << 6;
        const int d = d0 + lane;
        const float* Wl = W + l * DLv * RRv;
        float s = 0.f;
#pragma unroll
        for (int c = 0; c < 16; ++c) s += Wl[(wv * 16 + c) * RRv + d];
        aux[wv * 64 + lane] = s;
        __syncthreads();
        if (tid < 64)
            wbws[l * RRv + d0 + tid] =
                (aux[tid] + aux[64 + tid] + aux[128 + tid] + aux[192 + tid]) *
                (1.f / 64.f);
    }
    cg::this_grid().sync();

    // ---------- phase 2: P-GEMM (blocks 0..63) || t-colsum (64..95) ------
    const int tx = tid & 15, ty = tid >> 4;
    if (blk < 64) {
        // P[b][a] 32x32 tile: rows b = bm.., cols a = bn..
        const int bm = (blk >> 3) << 5, bn = (blk & 7) << 5;
        aux[tid] = wbws[tid];
        aux[256 + tid] = wbws[256 + tid];
        __syncthreads();
        float a00 = 0.f, a01 = 0.f, a10 = 0.f, a11 = 0.f;
        for (int k0 = 0; k0 < 512; k0 += 64) {
            const int l = k0 >> 8, d0 = k0 & 255;
            const float* Vl = V + l * DMv * RRv;
            const float* Ul = U + l * DMv * RRv;
            const float* wb = aux + l * 256 + d0;
#pragma unroll
            for (int j = 0; j < 2; ++j) {
                const int idx = tid + (j << 8);        // 0..511
                const int row = idx >> 4;              // 0..31
                const int c4 = (idx & 15) << 2;        // 0..60
                float4 av = *(const float4*)(Vl + (bm + row) * RRv + d0 + c4);
                As[c4 + 0][row] = av.x * wb[c4 + 0];
                As[c4 + 1][row] = av.y * wb[c4 + 1];
                As[c4 + 2][row] = av.z * wb[c4 + 2];
                As[c4 + 3][row] = av.w * wb[c4 + 3];
                float4 bv = *(const float4*)(Ul + (bn + row) * RRv + d0 + c4);
                Bs[c4 + 0][row] = bv.x;
                Bs[c4 + 1][row] = bv.y;
                Bs[c4 + 2][row] = bv.z;
                Bs[c4 + 3][row] = bv.w;
            }
            __syncthreads();
#pragma unroll
            for (int k = 0; k < 64; ++k) {
                float2 a = *(const float2*)&As[k][ty << 1];
                float2 b = *(const float2*)&Bs[k][tx << 1];
                a00 += a.x * b.x; a01 += a.x * b.y;
                a10 += a.y * b.x; a11 += a.y * b.y;
            }
            __syncthreads();
        }
        *(float2*)(P + (bm + (ty << 1)) * DMv + bn + (tx << 1)) =
            make_float2(a00, a01);
        *(float2*)(P + (bm + (ty << 1) + 1) * DMv + bn + (tx << 1)) =
            make_float2(a10, a11);
    } else if (blk < 96) {
        // t[z][d0..d0+31], computed ONCE (was 16x-redundant in R1's k_b)
        const int j = blk - 64, z = j >> 3, d0 = (j & 7) << 5;
        const int d = tid & 31, ig = tid >> 5;
        const float* q0 = qz + z * LLv * DMv + d0 + d;
        float s = 0.f;
#pragma unroll
        for (int i = 0; i < 32; ++i) s += q0[(ig * 32 + i) * DMv];
        aux[ig * 32 + d] = s;
        __syncthreads();
        if (tid < 32) {
            float t = 0.f;
#pragma unroll
            for (int g = 0; g < 8; ++g) t += aux[g * 32 + tid];
            tws[z * DMv + d0 + tid] = t;
        }
    }
    cg::this_grid().sync();

    // ---------- phase 3: out = x + valid * (t - qz) @ P, 32x32 tiles -----
    {
        const int bm = (blk >> 3) << 5, bn = (blk & 7) << 5;
        const int z = bm >> 8;
        aux[tid] = tws[z * DMv + tid];
        __syncthreads();
        float a00 = 0.f, a01 = 0.f, a10 = 0.f, a11 = 0.f;
        for (int k0 = 0; k0 < DMv; k0 += 64) {
#pragma unroll
            for (int j = 0; j < 2; ++j) {
                const int idx = tid + (j << 8);
                const int row = idx >> 4;              // 0..31 (m)
                const int c4 = (idx & 15) << 2;        // 0..60 (k)
                float4 av = *(const float4*)(qz + (bm + row) * DMv + k0 + c4);
                As[c4 + 0][row] = aux[k0 + c4 + 0] - av.x;
                As[c4 + 1][row] = aux[k0 + c4 + 1] - av.y;
                As[c4 + 2][row] = aux[k0 + c4 + 2] - av.z;
                As[c4 + 3][row] = aux[k0 + c4 + 3] - av.w;
                const int kr = idx >> 3;               // 0..63 (k)
                const int c4b = (idx & 7) << 2;        // 0..28 (n)
                float4 bv = *(const float4*)(P + (k0 + kr) * DMv + bn + c4b);
                *(float4*)&Bs[kr][c4b] = bv;           // 144B rows: aligned
            }
            __syncthreads();
#pragma unroll
            for (int k = 0; k < 64; ++k) {
                float2 a = *(const float2*)&As[k][ty << 1];
                float2 b = *(const float2*)&Bs[k][tx << 1];
                a00 += a.x * b.x; a01 += a.x * b.y;
                a10 += a.y * b.x; a11 += a.y * b.y;
            }
            __syncthreads();
        }
        const int r0 = bm + (ty << 1), col = bn + (tx << 1);
        const float v0 = (mask[r0] != 0) ? 1.f : 0.f;
        const float v1 = (mask[r0 + 1] != 0) ? 1.f : 0.f;
        float2 x0 = *(const float2*)(x + r0 * DMv + col);
        float2 x1 = *(const float2*)(x + (r0 + 1) * DMv + col);
        *(float2*)(out + r0 * DMv + col) =
            make_float2(x0.x + v0 * a00, x0.y + v0 * a01);
        *(float2*)(out + (r0 + 1) * DMv + col) =
            make_float2(x1.x + v1 * a10, x1.y + v1 * a11);
    }
}

extern "C" void kernel_launch(void* const* d_in, const int* in_sizes, int n_in,
                              void* d_out, int out_size, void* d_ws, size_t ws_size,
                              hipStream_t stream) {
    const float* x    = (const float*)d_in[0];   // (4,256,256)
    const float* U    = (const float*)d_in[1];   // (2,1,256,256)
    const float* V    = (const float*)d_in[2];   // (2,1,256,256)
    const float* W    = (const float*)d_in[3];   // (2,1,64,256)
    const int*   mask = (const int*)d_in[4];     // (4,256)
    float* out = (float*)d_out;                  // (4,256,256)

    float* qz   = (float*)d_ws;        // 262144 floats (1 MB)
    float* P    = qz + 262144;         // 65536 floats (256 KB)
    float* tws  = P + 65536;           // 1024 floats
    float* wbws = tws + 1024;          // 512 floats

    void* args[] = {(void*)&x, (void*)&mask, (void*)&U, (void*)&V, (void*)&W,
                    (void*)&qz, (void*)&P, (void*)&tws, (void*)&wbws,
                    (void*)&out};
    hipLaunchCooperativeKernel(reinterpret_cast<void*>(k_all), dim3(256),
                               dim3(256), args, 0, stream);
}

// Round 3
// 88.232 us; speedup vs baseline: 1.7405x; 1.7405x over previous
//
#include <hip/hip_runtime.h>

// Problem constants: B=4, L=256, DM=256, DL=64, R=256, K=1,
// N_ITER=4, STEPSIZE=1.0, DAMPING=0.0, REG=1.0.
//
// Algebraic collapse (verified exact, absmax 0.0): output is ONE pass:
//   qz   = valid * softmax(x, -1)                       (B*L, DM)
//   t[z] = sum_i qz[z,i,:]                              (B, DM)
//   wbar[l,d] = mean_c W[l,c,d]                         (2, R)
//   P[b,a]   = sum_{l,d} V[l,b,d]*wbar[l,d]*U[l,a,d]    (DM, DM)
//   out[z,i,a] = x[z,i,a] + valid_i * sum_b (t[z,b]-qz[z,i,b]) * P[b,a]
//
// R5: two launches (grid-sync proved ~25-30us/sync in R2 -> reverted).
// Kernel A (320 blocks): 256 softmax blocks (4 wave-per-row rows each,
// syncless, emit per-block partial t into pt) + 64 P-GEMM blocks (32x32
// tiles, per-block redundant wbar). Kernel B (256 blocks): t = 64-partial
// reduce (coalesced) + 32x32 out-GEMM tile + epilogue. Fill floor ~83us is
// harness reset; controllable share targeted at ~15us.

#define DMv 256
#define LLv 256
#define RRv 256
#define DLv 64

__global__ __launch_bounds__(256) void k_a(
    const float* __restrict__ x, const int* __restrict__ mask,
    const float* __restrict__ U, const float* __restrict__ V,
    const float* __restrict__ W, float* __restrict__ qz,
    float* __restrict__ P, float* __restrict__ pt) {
    // union: softmax uses first 1024 floats; P-GEMM uses aux[512] + As/Bs
    __shared__ float smem[512 + 2 * 64 * 36];
    float* aux = smem;
    float (*As)[36] = (float (*)[36])(smem + 512);
    float (*Bs)[36] = (float (*)[36])(smem + 512 + 64 * 36);
    const int tid = threadIdx.x;
    const int blk = blockIdx.x;
    const int lane = tid & 63;
    const int wv = tid >> 6;

    if (blk < 256) {
        // ---- softmax: 4 rows per block (wave per row), + partial t ----
        const int row = (blk << 2) + wv;
        float4 v = *(const float4*)(x + row * DMv + (lane << 2));
        float m = fmaxf(fmaxf(v.x, v.y), fmaxf(v.z, v.w));
#pragma unroll
        for (int o = 32; o > 0; o >>= 1) m = fmaxf(m, __shfl_xor(m, o, 64));
        float e0 = __expf(v.x - m), e1 = __expf(v.y - m);
        float e2 = __expf(v.z - m), e3 = __expf(v.w - m);
        float s = e0 + e1 + e2 + e3;
#pragma unroll
        for (int o = 32; o > 0; o >>= 1) s += __shfl_xor(s, o, 64);
        float4 q;
        if (mask[row] != 0) {
            float r = 1.0f / s;
            q.x = e0 * r; q.y = e1 * r; q.z = e2 * r; q.w = e3 * r;
        } else {
            q.x = 0.f; q.y = 0.f; q.z = 0.f; q.w = 0.f;
        }
        *(float4*)(qz + row * DMv + (lane << 2)) = q;
        // partial t for this block's 4 rows: LDS reduce across waves
        *(float4*)(smem + wv * 256 + (lane << 2)) = q;
        __syncthreads();
        pt[blk * 256 + tid] =
            smem[tid] + smem[256 + tid] + smem[512 + tid] + smem[768 + tid];
        return;
    }

    // ---- P-GEMM: 64 blocks, 32x32 tiles, K=512 (l,d) ----
    const int pb = blk - 256;                    // 0..63
    const int bm = (pb >> 3) << 5, bn = (pb & 7) << 5;
    // wbar computed per block: aux[l*256+d] = mean_c W[l][c][d]
#pragma unroll
    for (int l = 0; l < 2; ++l) {
        const float* Wl = W + l * DLv * RRv;
        float s = 0.f;
#pragma unroll
        for (int c = 0; c < DLv; ++c) s += Wl[c * RRv + tid];
        aux[l * 256 + tid] = s * (1.f / 64.f);
    }
    __syncthreads();

    const int tx = tid & 15, ty = tid >> 4;
    float a00 = 0.f, a01 = 0.f, a10 = 0.f, a11 = 0.f;
    for (int k0 = 0; k0 < 512; k0 += 64) {
        const int l = k0 >> 8, d0 = k0 & 255;
        const float* Vl = V + l * DMv * RRv;
        const float* Ul = U + l * DMv * RRv;
        const float* wb = aux + l * 256 + d0;
#pragma unroll
        for (int j = 0; j < 2; ++j) {
            const int idx = tid + (j << 8);        // 0..511
            const int row = idx >> 4;              // 0..31
            const int c4 = (idx & 15) << 2;        // 0..60
            float4 av = *(const float4*)(Vl + (bm + row) * RRv + d0 + c4);
            As[c4 + 0][row] = av.x * wb[c4 + 0];
            As[c4 + 1][row] = av.y * wb[c4 + 1];
            As[c4 + 2][row] = av.z * wb[c4 + 2];
            As[c4 + 3][row] = av.w * wb[c4 + 3];
            float4 bv = *(const float4*)(Ul + (bn + row) * RRv + d0 + c4);
            Bs[c4 + 0][row] = bv.x;
            Bs[c4 + 1][row] = bv.y;
            Bs[c4 + 2][row] = bv.z;
            Bs[c4 + 3][row] = bv.w;
        }
        __syncthreads();
#pragma unroll
        for (int k = 0; k < 64; ++k) {
            float2 a = *(const float2*)&As[k][ty << 1];
            float2 b = *(const float2*)&Bs[k][tx << 1];
            a00 += a.x * b.x; a01 += a.x * b.y;
            a10 += a.y * b.x; a11 += a.y * b.y;
        }
        __syncthreads();
    }
    *(float2*)(P + (bm + (ty << 1)) * DMv + bn + (tx << 1)) =
        make_float2(a00, a01);
    *(float2*)(P + (bm + (ty << 1) + 1) * DMv + bn + (tx << 1)) =
        make_float2(a10, a11);
}

__global__ __launch_bounds__(256) void k_b(
    const float* __restrict__ x, const int* __restrict__ mask,
    const float* __restrict__ qz, const float* __restrict__ P,
    const float* __restrict__ pt, float* __restrict__ out) {
    __shared__ float smem[512 + 2 * 64 * 36];
    float* aux = smem;                           // t[z][0..255]
    float (*As)[36] = (float (*)[36])(smem + 512);
    float (*Bs)[36] = (float (*)[36])(smem + 512 + 64 * 36);
    const int tid = threadIdx.x;
    const int blk = blockIdx.x;
    const int bm = (blk >> 3) << 5, bn = (blk & 7) << 5;
    const int z = bm >> 8;

    // ---- t[z][tid] = sum of 64 per-block partials (coalesced) ----
    {
        const float* p0 = pt + z * 64 * 256 + tid;
        float s = 0.f;
#pragma unroll
        for (int i = 0; i < 64; ++i) s += p0[i * 256];
        aux[tid] = s;
    }
    __syncthreads();

    // ---- 32x32 out-GEMM tile, K=256 ----
    const int tx = tid & 15, ty = tid >> 4;
    float a00 = 0.f, a01 = 0.f, a10 = 0.f, a11 = 0.f;
    for (int k0 = 0; k0 < DMv; k0 += 64) {
#pragma unroll
        for (int j = 0; j < 2; ++j) {
            const int idx = tid + (j << 8);
            const int row = idx >> 4;              // 0..31 (m)
            const int c4 = (idx & 15) << 2;        // 0..60 (k)
            float4 av = *(const float4*)(qz + (bm + row) * DMv + k0 + c4);
            As[c4 + 0][row] = aux[k0 + c4 + 0] - av.x;
            As[c4 + 1][row] = aux[k0 + c4 + 1] - av.y;
            As[c4 + 2][row] = aux[k0 + c4 + 2] - av.z;
            As[c4 + 3][row] = aux[k0 + c4 + 3] - av.w;
            const int kr = idx >> 3;               // 0..63 (k)
            const int c4b = (idx & 7) << 2;        // 0..28 (n)
            float4 bv = *(const float4*)(P + (k0 + kr) * DMv + bn + c4b);
            *(float4*)&Bs[kr][c4b] = bv;           // 144B rows: 16B-aligned
        }
        __syncthreads();
#pragma unroll
        for (int k = 0; k < 64; ++k) {
            float2 a = *(const float2*)&As[k][ty << 1];
            float2 b = *(const float2*)&Bs[k][tx << 1];
            a00 += a.x * b.x; a01 += a.x * b.y;
            a10 += a.y * b.x; a11 += a.y * b.y;
        }
        __syncthreads();
    }
    const int r0 = bm + (ty << 1), col = bn + (tx << 1);
    const float v0 = (mask[r0] != 0) ? 1.f : 0.f;
    const float v1 = (mask[r0 + 1] != 0) ? 1.f : 0.f;
    float2 x0 = *(const float2*)(x + r0 * DMv + col);
    float2 x1 = *(const float2*)(x + (r0 + 1) * DMv + col);
    *(float2*)(out + r0 * DMv + col) =
        make_float2(x0.x + v0 * a00, x0.y + v0 * a01);
    *(float2*)(out + (r0 + 1) * DMv + col) =
        make_float2(x1.x + v1 * a10, x1.y + v1 * a11);
}

extern "C" void kernel_launch(void* const* d_in, const int* in_sizes, int n_in,
                              void* d_out, int out_size, void* d_ws, size_t ws_size,
                              hipStream_t stream) {
    const float* x    = (const float*)d_in[0];   // (4,256,256)
    const float* U    = (const float*)d_in[1];   // (2,1,256,256)
    const float* V    = (const float*)d_in[2];   // (2,1,256,256)
    const float* W    = (const float*)d_in[3];   // (2,1,64,256)
    const int*   mask = (const int*)d_in[4];     // (4,256)
    float* out = (float*)d_out;                  // (4,256,256)

    float* qz = (float*)d_ws;          // 262144 floats (1 MB)
    float* P  = qz + 262144;           // 65536 floats (256 KB)
    float* pt = P + 65536;             // 65536 floats (256 KB)

    hipLaunchKernelGGL(k_a, dim3(320), dim3(256), 0, stream,
                       x, mask, U, V, W, qz, P, pt);
    hipLaunchKernelGGL(k_b, dim3(256), dim3(256), 0, stream,
                       x, mask, qz, P, pt, out);
}